// Round 3
// baseline (547.141 us; speedup 1.0000x reference)
//
#include <hip/hip_runtime.h>

typedef __bf16 bf16;
typedef __bf16 bf16x2 __attribute__((ext_vector_type(2)));
typedef __bf16 bf16x4 __attribute__((ext_vector_type(4)));
typedef __bf16 bf16x8 __attribute__((ext_vector_type(8)));
typedef float f32x4 __attribute__((ext_vector_type(4)));

// ---------------------------------------------------------------------------
// GEMM: C[M,N] = A[M,K] * B[N,K]^T (+bias), MFMA bf16, fp32 accumulate.
// (unchanged — proven)
// ---------------------------------------------------------------------------
template <typename TA, typename TC, bool ADD_BIAS>
__global__ __launch_bounds__(256) void gemm_bt(const TA* __restrict__ A,
                                               const float* __restrict__ B,
                                               const float* __restrict__ bias,
                                               TC* __restrict__ C,
                                               int M, int N, int K,
                                               int lda, int row0) {
  __shared__ __align__(16) bf16 As[128][72];
  __shared__ __align__(16) bf16 Bs[128][72];
  const int tid = threadIdx.x;
  const int lane = tid & 63;
  const int wid = tid >> 6;
  const int wr = wid >> 1, wc = wid & 1;
  const int m0 = blockIdx.y * 128;
  const int n0 = blockIdx.x * 128;
  const int l16 = lane & 15;
  const int lhi = lane >> 4;

  f32x4 acc[4][4] = {};

  for (int k0 = 0; k0 < K; k0 += 64) {
    __syncthreads();
#pragma unroll
    for (int p = 0; p < 8; ++p) {
      int v = tid + p * 256;
      int row = v >> 4;
      int kc = (v & 15) * 4;
      size_t ai = (size_t)(row0 + m0 + row) * lda + k0 + kc;
      size_t bi = (size_t)(n0 + row) * K + k0 + kc;
      bf16x4 ab, bb;
      if constexpr (__is_same(TA, float)) {
        f32x4 a4 = *(const f32x4*)((const float*)A + ai);
#pragma unroll
        for (int j = 0; j < 4; ++j) ab[j] = (bf16)a4[j];
      } else {
        ab = *(const bf16x4*)((const bf16*)A + ai);
      }
      f32x4 b4 = *(const f32x4*)(B + bi);
#pragma unroll
      for (int j = 0; j < 4; ++j) bb[j] = (bf16)b4[j];
      *(bf16x4*)(&As[row][kc]) = ab;
      *(bf16x4*)(&Bs[row][kc]) = bb;
    }
    __syncthreads();
#pragma unroll
    for (int ks = 0; ks < 2; ++ks) {
      bf16x8 af[4], bfr[4];
#pragma unroll
      for (int i = 0; i < 4; ++i) {
        af[i] = *(const bf16x8*)(&As[wr * 64 + i * 16 + l16][ks * 32 + lhi * 8]);
        bfr[i] = *(const bf16x8*)(&Bs[wc * 64 + i * 16 + l16][ks * 32 + lhi * 8]);
      }
#pragma unroll
      for (int i = 0; i < 4; ++i)
#pragma unroll
        for (int j = 0; j < 4; ++j)
          acc[i][j] = __builtin_amdgcn_mfma_f32_16x16x32_bf16(af[i], bfr[j],
                                                              acc[i][j], 0, 0, 0);
    }
  }

#pragma unroll
  for (int i = 0; i < 4; ++i) {
    int row_base = m0 + wr * 64 + i * 16 + lhi * 4;
#pragma unroll
    for (int j = 0; j < 4; ++j) {
      int col = n0 + wc * 64 + j * 16 + l16;
      float bv = ADD_BIAS ? bias[col] : 0.0f;
#pragma unroll
      for (int r = 0; r < 4; ++r) {
        float val = acc[i][j][r] + bv;
        if constexpr (__is_same(TC, float))
          C[(size_t)(row_base + r) * N + col] = val;
        else
          C[(size_t)(row_base + r) * N + col] = (bf16)val;
      }
    }
  }
}

// ---------------------------------------------------------------------------
// MFMA flash attention v5.
//  - XCD swizzle kept (round-1: FETCH 139 MB -> 35 MB, proven).
//  - plain __launch_bounds__(256): round-1's (256,8) forced VGPR=32 -> spill
//    (WRITE_SIZE 16->37 MB, +8% dur); (256,6) aborted the harness. Default
//    bound is the round-0 proven config; compiler picks ~76-96 VGPR, no
//    spill, natural 5-6 waves/SIMD (LDS 18.4 KB would allow 8 blocks/CU).
//  - async V-prefetch (registers), exp2-direct softmax, defer-max rescale,
//    setprio around MFMA clusters: all kept.
//  - LDS stride 72 kept for size (bank-conflict-neutral vs 80 by arithmetic:
//    both at the b128 consecutive-lane-phase floor; round-1 counter confirmed).
// ---------------------------------------------------------------------------
__global__ __launch_bounds__(256) void attn_fwd(bf16* __restrict__ qkv) {
  constexpr int S = 2048, D3 = 3072;
  constexpr float SCL = 0.18033688011112042f;  // 0.125 * log2(e)
  __shared__ __align__(16) bf16 Vt[64][72];     // [dim][key], 144 B stride
  __shared__ __align__(16) bf16 Pq[4][16][72];  // per-wave [qrow][key]

  const int tid = threadIdx.x;
  const int lane = tid & 63;
  const int wid = tid >> 6;
  const int l16 = lane & 15, lhi = lane >> 4;

  // XCD-aware bijective swizzle (nwg % 8 == 0 in both launch paths).
  const int nwg = gridDim.x * gridDim.y;        // 2048 (full) / 512 (fallback)
  const int bid = blockIdx.y * 32 + blockIdx.x; // gridDim.x == 32
  const int swz = (bid & 7) * (nwg >> 3) + (bid >> 3);
  const int bh = swz >> 5;                      // 32 q-tiles per bh
  const int b = bh >> 4, h = bh & 15;
  const int q0 = (swz & 31) * 64 + wid * 16;

  bf16* base = qkv + (size_t)b * S * D3;
  bf16* qbase = base + h * 64;
  const bf16* kbase = base + 1024 + h * 64;
  const bf16* vbase = base + 2048 + h * 64;

  // Q fragments, B-operand: n(qrow)=l16, k=lhi*8+j (cached before overwrite)
  bf16x8 qf[2];
#pragma unroll
  for (int ks = 0; ks < 2; ++ks)
    qf[ks] = *(const bf16x8*)(qbase + (size_t)(q0 + l16) * D3 + ks * 32 + lhi * 8);

  float m_i = -1e30f, l_i = 0.0f;  // per-lane: q-row = q0 + l16 (log2 domain)
  f32x4 o[4] = {};

  const int kp = tid & 31, oc = tid >> 5;
  // prologue: V loads for t = 0
  bf16x8 v0 = *(const bf16x8*)(vbase + (size_t)(2 * kp) * D3 + oc * 8);
  bf16x8 v1 = *(const bf16x8*)(vbase + (size_t)(2 * kp + 1) * D3 + oc * 8);

  for (int t = 0; t < S; t += 64) {
    __syncthreads();  // prev iteration's PV reads of Vt done
    // V stage write: key-pair kp (keys 2kp,2kp+1), dim octet oc
#pragma unroll
    for (int j = 0; j < 8; ++j) {
      bf16x2 pr;
      pr[0] = v0[j];
      pr[1] = v1[j];
      *(bf16x2*)(&Vt[oc * 8 + j][2 * kp]) = pr;
    }
    __syncthreads();  // Vt ready

    // K·Q^T: sc[ct][r] = score(key = t + ct*16 + lhi*4 + r, qrow = l16)
    f32x4 sc[4] = {};
    __builtin_amdgcn_s_setprio(1);
#pragma unroll
    for (int ct = 0; ct < 4; ++ct) {
#pragma unroll
      for (int ks = 0; ks < 2; ++ks) {
        bf16x8 kf = *(const bf16x8*)(kbase + (size_t)(t + ct * 16 + l16) * D3 +
                                     ks * 32 + lhi * 8);
        sc[ct] = __builtin_amdgcn_mfma_f32_16x16x32_bf16(kf, qf[ks], sc[ct], 0, 0, 0);
      }
    }
    __builtin_amdgcn_s_setprio(0);

    // online softmax in log2 domain, scalar state per lane (one q-row)
    float cm[4];
#pragma unroll
    for (int ct = 0; ct < 4; ++ct)
      cm[ct] = fmaxf(fmaxf(sc[ct][0], sc[ct][1]), fmaxf(sc[ct][2], sc[ct][3]));
    float mx = fmaxf(fmaxf(cm[0], cm[1]), fmaxf(cm[2], cm[3]));
    mx = fmaxf(mx, __shfl_xor(mx, 16));
    mx = fmaxf(mx, __shfl_xor(mx, 32));
    mx *= SCL;

    // defer-max: skip O/l rescale unless tile max grew past THR (=8*log2e)
    if (!__all(mx - m_i <= 11.5f)) {
      float nm = fmaxf(m_i, mx);
      float alpha = __builtin_amdgcn_exp2f(m_i - nm);
      m_i = nm;
      l_i *= alpha;
#pragma unroll
      for (int dt = 0; dt < 4; ++dt)
#pragma unroll
        for (int r = 0; r < 4; ++r) o[dt][r] *= alpha;
    }

    // async V-stage split: issue next tile's V loads; consumed next iteration
    if (t + 64 < S) {
      v0 = *(const bf16x8*)(vbase + (size_t)(t + 64 + 2 * kp) * D3 + oc * 8);
      v1 = *(const bf16x8*)(vbase + (size_t)(t + 64 + 2 * kp + 1) * D3 + oc * 8);
    }

    float rs4[4];
#pragma unroll
    for (int ct = 0; ct < 4; ++ct) {
#pragma unroll
      for (int r = 0; r < 4; ++r) {
        float p = __builtin_amdgcn_exp2f(__builtin_fmaf(sc[ct][r], SCL, -m_i));
        sc[ct][r] = p;
      }
      rs4[ct] = (sc[ct][0] + sc[ct][1]) + (sc[ct][2] + sc[ct][3]);
    }
    float rs = (rs4[0] + rs4[1]) + (rs4[2] + rs4[3]);
    rs += __shfl_xor(rs, 16);
    rs += __shfl_xor(rs, 32);
    l_i += rs;

    // P stage: Pq[qrow][key] = P[key][qrow]; 4x packed ds_write_b64
#pragma unroll
    for (int ct = 0; ct < 4; ++ct) {
      bf16x4 pk;
#pragma unroll
      for (int r = 0; r < 4; ++r) pk[r] = (bf16)sc[ct][r];
      *(bf16x4*)(&Pq[wid][l16][ct * 16 + lhi * 4]) = pk;
    }
    bf16x8 pf0 = *(const bf16x8*)(&Pq[wid][l16][lhi * 8]);
    bf16x8 pf1 = *(const bf16x8*)(&Pq[wid][l16][32 + lhi * 8]);

    // PV: o[m=dh][n=qrow] += V^T x P ; A-frag from Vt
    __builtin_amdgcn_s_setprio(1);
#pragma unroll
    for (int dt = 0; dt < 4; ++dt) {
      bf16x8 vf0 = *(const bf16x8*)(&Vt[dt * 16 + l16][lhi * 8]);
      bf16x8 vf1 = *(const bf16x8*)(&Vt[dt * 16 + l16][32 + lhi * 8]);
      o[dt] = __builtin_amdgcn_mfma_f32_16x16x32_bf16(vf0, pf0, o[dt], 0, 0, 0);
      o[dt] = __builtin_amdgcn_mfma_f32_16x16x32_bf16(vf1, pf1, o[dt], 0, 0, 0);
    }
    __builtin_amdgcn_s_setprio(0);
  }

  // epilogue: O[qrow=l16][dh=dt*16+lhi*4+r]/l -> transpose via Pq -> 16B stores
  float rl = 1.0f / l_i;
#pragma unroll
  for (int dt = 0; dt < 4; ++dt) {
    bf16x4 ok;
#pragma unroll
    for (int r = 0; r < 4; ++r) ok[r] = (bf16)(o[dt][r] * rl);
    *(bf16x4*)(&Pq[wid][l16][dt * 16 + lhi * 4]) = ok;
  }
  bf16x8 r0 = *(const bf16x8*)(&Pq[wid][l16][lhi * 16]);
  bf16x8 r1 = *(const bf16x8*)(&Pq[wid][l16][lhi * 16 + 8]);
  bf16* orow = qbase + (size_t)(q0 + l16) * D3 + lhi * 16;
  *(bf16x8*)(orow) = r0;
  *(bf16x8*)(orow + 8) = r1;
}

// ---------------------------------------------------------------------------
extern "C" void kernel_launch(void* const* d_in, const int* in_sizes, int n_in,
                              void* d_out, int out_size, void* d_ws,
                              size_t ws_size, hipStream_t stream) {
  constexpr int B = 4, S = 2048, D = 1024;

  const float* x = nullptr;
  const float* w_in = nullptr;
  const float* w_out = nullptr;
  const float* b_out = nullptr;
  for (int i = 0; i < n_in; ++i) {
    switch (in_sizes[i]) {
      case 8388608: x = (const float*)d_in[i]; break;
      case 3145728: w_in = (const float*)d_in[i]; break;
      case 1048576: w_out = (const float*)d_in[i]; break;
      case 1024: b_out = (const float*)d_in[i]; break;
    }
  }
  float* out = (float*)d_out;  // [4,2048,1024] fp32

  bf16* qkv = (bf16*)d_ws;
  const size_t need_full = (size_t)B * S * 3 * D * 2;  // 48 MiB

  if (ws_size >= need_full) {
    gemm_bt<float, bf16, false><<<dim3(3 * D / 128, B * S / 128), 256, 0,
                                  stream>>>(x, w_in, nullptr, qkv, B * S,
                                            3 * D, D, D, 0);
    attn_fwd<<<dim3(S / 64, B * 16), 256, 0, stream>>>(qkv);
    gemm_bt<bf16, float, true><<<dim3(D / 128, B * S / 128), 256, 0, stream>>>(
        qkv, w_out, b_out, out, B * S, D, D, 3 * D, 0);
  } else {
    for (int b0 = 0; b0 < B; ++b0) {
      gemm_bt<float, bf16, false><<<dim3(3 * D / 128, S / 128), 256, 0,
                                    stream>>>(x, w_in, nullptr, qkv, S, 3 * D,
                                              D, D, b0 * S);
      attn_fwd<<<dim3(S / 64, 16), 256, 0, stream>>>(qkv);
      gemm_bt<bf16, float, true><<<dim3(D / 128, S / 128), 256, 0, stream>>>(
          qkv, w_out, b_out, out + (size_t)b0 * S * D, S, D, D, 3 * D, 0);
    }
  }
}

// Round 4
// 513.910 us; speedup vs baseline: 1.0647x; 1.0647x over previous
//
#include <hip/hip_runtime.h>

typedef __bf16 bf16;
typedef __bf16 bf16x2 __attribute__((ext_vector_type(2)));
typedef __bf16 bf16x4 __attribute__((ext_vector_type(4)));
typedef __bf16 bf16x8 __attribute__((ext_vector_type(8)));
typedef float f32x4 __attribute__((ext_vector_type(4)));

// ---------------------------------------------------------------------------
// GEMM: C[M,N] = A[M,K] * B[N,K]^T (+bias), MFMA bf16, fp32 accumulate.
// (unchanged — proven)
// ---------------------------------------------------------------------------
template <typename TA, typename TC, bool ADD_BIAS>
__global__ __launch_bounds__(256) void gemm_bt(const TA* __restrict__ A,
                                               const float* __restrict__ B,
                                               const float* __restrict__ bias,
                                               TC* __restrict__ C,
                                               int M, int N, int K,
                                               int lda, int row0) {
  __shared__ __align__(16) bf16 As[128][72];
  __shared__ __align__(16) bf16 Bs[128][72];
  const int tid = threadIdx.x;
  const int lane = tid & 63;
  const int wid = tid >> 6;
  const int wr = wid >> 1, wc = wid & 1;
  const int m0 = blockIdx.y * 128;
  const int n0 = blockIdx.x * 128;
  const int l16 = lane & 15;
  const int lhi = lane >> 4;

  f32x4 acc[4][4] = {};

  for (int k0 = 0; k0 < K; k0 += 64) {
    __syncthreads();
#pragma unroll
    for (int p = 0; p < 8; ++p) {
      int v = tid + p * 256;
      int row = v >> 4;
      int kc = (v & 15) * 4;
      size_t ai = (size_t)(row0 + m0 + row) * lda + k0 + kc;
      size_t bi = (size_t)(n0 + row) * K + k0 + kc;
      bf16x4 ab, bb;
      if constexpr (__is_same(TA, float)) {
        f32x4 a4 = *(const f32x4*)((const float*)A + ai);
#pragma unroll
        for (int j = 0; j < 4; ++j) ab[j] = (bf16)a4[j];
      } else {
        ab = *(const bf16x4*)((const bf16*)A + ai);
      }
      f32x4 b4 = *(const f32x4*)(B + bi);
#pragma unroll
      for (int j = 0; j < 4; ++j) bb[j] = (bf16)b4[j];
      *(bf16x4*)(&As[row][kc]) = ab;
      *(bf16x4*)(&Bs[row][kc]) = bb;
    }
    __syncthreads();
#pragma unroll
    for (int ks = 0; ks < 2; ++ks) {
      bf16x8 af[4], bfr[4];
#pragma unroll
      for (int i = 0; i < 4; ++i) {
        af[i] = *(const bf16x8*)(&As[wr * 64 + i * 16 + l16][ks * 32 + lhi * 8]);
        bfr[i] = *(const bf16x8*)(&Bs[wc * 64 + i * 16 + l16][ks * 32 + lhi * 8]);
      }
#pragma unroll
      for (int i = 0; i < 4; ++i)
#pragma unroll
        for (int j = 0; j < 4; ++j)
          acc[i][j] = __builtin_amdgcn_mfma_f32_16x16x32_bf16(af[i], bfr[j],
                                                              acc[i][j], 0, 0, 0);
    }
  }

#pragma unroll
  for (int i = 0; i < 4; ++i) {
    int row_base = m0 + wr * 64 + i * 16 + lhi * 4;
#pragma unroll
    for (int j = 0; j < 4; ++j) {
      int col = n0 + wc * 64 + j * 16 + l16;
      float bv = ADD_BIAS ? bias[col] : 0.0f;
#pragma unroll
      for (int r = 0; r < 4; ++r) {
        float val = acc[i][j][r] + bv;
        if constexpr (__is_same(TC, float))
          C[(size_t)(row_base + r) * N + col] = val;
        else
          C[(size_t)(row_base + r) * N + col] = (bf16)val;
      }
    }
  }
}

// ---------------------------------------------------------------------------
// MFMA flash attention v6.
//  - XCD swizzle kept (FETCH 139 -> 24.6 MB, proven r1/r3).
//  - SHUFFLE-FREE common-path softmax: per-tile l-sum deferred to epilogue
//    (per-lane partial; valid since m_i/alpha uniform across the 4 lanes of a
//    q-row), and defer-max check uses IN-LANE max + __all (no reduce). Full
//    2-shuffle max reduce only in the rare rescale branch. Was 4 crossbar
//    ops/tile on the critical path (r3 theory: they ARE the 1.49e7
//    "bank-conflict" cycles).
//  - Double-buffered Vt: ONE barrier per tile (was 2). V loads for tile t+1
//    issued at top of iter t, LDS-written after softmax -> latency hidden.
//  - exp2-direct softmax, setprio around MFMA clusters kept.
// ---------------------------------------------------------------------------
__global__ __launch_bounds__(256) void attn_fwd(bf16* __restrict__ qkv) {
  constexpr int S = 2048, D3 = 3072;
  constexpr float SCL = 0.18033688011112042f;  // 0.125 * log2(e)
  constexpr float THR = 11.5f;                 // 8 * log2(e), log2 domain
  __shared__ __align__(16) bf16 Vt[2][64][72];  // [buf][dim][key]
  __shared__ __align__(16) bf16 Pq[4][16][72];  // per-wave [qrow][key]

  const int tid = threadIdx.x;
  const int lane = tid & 63;
  const int wid = tid >> 6;
  const int l16 = lane & 15, lhi = lane >> 4;

  // XCD-aware bijective swizzle (nwg % 8 == 0 in both launch paths).
  const int nwg = gridDim.x * gridDim.y;        // 2048 (full) / 512 (fallback)
  const int bid = blockIdx.y * 32 + blockIdx.x; // gridDim.x == 32
  const int swz = (bid & 7) * (nwg >> 3) + (bid >> 3);
  const int bh = swz >> 5;                      // 32 q-tiles per bh
  const int b = bh >> 4, h = bh & 15;
  const int q0 = (swz & 31) * 64 + wid * 16;

  bf16* base = qkv + (size_t)b * S * D3;
  bf16* qbase = base + h * 64;
  const bf16* kbase = base + 1024 + h * 64;
  const bf16* vbase = base + 2048 + h * 64;

  // Q fragments, B-operand: n(qrow)=l16, k=lhi*8+j (cached before overwrite)
  bf16x8 qf[2];
#pragma unroll
  for (int ks = 0; ks < 2; ++ks)
    qf[ks] = *(const bf16x8*)(qbase + (size_t)(q0 + l16) * D3 + ks * 32 + lhi * 8);

  float m_i = -1e30f;    // running max, log2 domain, uniform per q-row
  float l_part = 0.0f;   // PER-LANE partial sum; reduced once in epilogue
  f32x4 o[4] = {};

  const int kp = tid & 31, oc = tid >> 5;

  // prologue: stage V(0) into Vt[0]
  {
    bf16x8 v0 = *(const bf16x8*)(vbase + (size_t)(2 * kp) * D3 + oc * 8);
    bf16x8 v1 = *(const bf16x8*)(vbase + (size_t)(2 * kp + 1) * D3 + oc * 8);
#pragma unroll
    for (int j = 0; j < 8; ++j) {
      bf16x2 pr;
      pr[0] = v0[j];
      pr[1] = v1[j];
      *(bf16x2*)(&Vt[0][oc * 8 + j][2 * kp]) = pr;
    }
  }
  __syncthreads();

  for (int t = 0; t < S; t += 64) {
    const int cur = (t >> 6) & 1;
    const bool havenext = (t + 64 < S);

    // issue next tile's V loads FIRST — hidden under QKT + softmax
    bf16x8 v0, v1;
    if (havenext) {
      v0 = *(const bf16x8*)(vbase + (size_t)(t + 64 + 2 * kp) * D3 + oc * 8);
      v1 = *(const bf16x8*)(vbase + (size_t)(t + 64 + 2 * kp + 1) * D3 + oc * 8);
    }

    // K·Q^T: sc[ct][r] = score(key = t + ct*16 + lhi*4 + r, qrow = l16)
    f32x4 sc[4] = {};
    __builtin_amdgcn_s_setprio(1);
#pragma unroll
    for (int ct = 0; ct < 4; ++ct) {
#pragma unroll
      for (int ks = 0; ks < 2; ++ks) {
        bf16x8 kf = *(const bf16x8*)(kbase + (size_t)(t + ct * 16 + l16) * D3 +
                                     ks * 32 + lhi * 8);
        sc[ct] = __builtin_amdgcn_mfma_f32_16x16x32_bf16(kf, qf[ks], sc[ct], 0, 0, 0);
      }
    }
    __builtin_amdgcn_s_setprio(0);

    // in-lane max (16 keys) — NO cross-lane ops in the common path
    float cm[4];
#pragma unroll
    for (int ct = 0; ct < 4; ++ct)
      cm[ct] = fmaxf(fmaxf(sc[ct][0], sc[ct][1]), fmaxf(sc[ct][2], sc[ct][3]));
    float mxs = fmaxf(fmaxf(cm[0], cm[1]), fmaxf(cm[2], cm[3])) * SCL;

    // defer-max: rescale only if some lane's tile max exceeds m_i + THR.
    // Rare branch (first tile + occasional growth) does the full reduce;
    // m_i stays uniform across the 4 lanes of each q-row.
    if (!__all(mxs - m_i <= THR)) {
      float mw = mxs;
      mw = fmaxf(mw, __shfl_xor(mw, 16));
      mw = fmaxf(mw, __shfl_xor(mw, 32));
      float nm = fmaxf(m_i, mw);
      float alpha = __builtin_amdgcn_exp2f(m_i - nm);
      m_i = nm;
      l_part *= alpha;
#pragma unroll
      for (int dt = 0; dt < 4; ++dt)
#pragma unroll
        for (int r = 0; r < 4; ++r) o[dt][r] *= alpha;
    }

    // stage V(t+1) into the other buffer (published by end-of-iter barrier)
    if (havenext) {
#pragma unroll
      for (int j = 0; j < 8; ++j) {
        bf16x2 pr;
        pr[0] = v0[j];
        pr[1] = v1[j];
        *(bf16x2*)(&Vt[cur ^ 1][oc * 8 + j][2 * kp]) = pr;
      }
    }

    // P = exp2(s*SCL - m_i); per-lane partial sum (no reduce)
    float rs4[4];
#pragma unroll
    for (int ct = 0; ct < 4; ++ct) {
#pragma unroll
      for (int r = 0; r < 4; ++r) {
        float p = __builtin_amdgcn_exp2f(__builtin_fmaf(sc[ct][r], SCL, -m_i));
        sc[ct][r] = p;
      }
      rs4[ct] = (sc[ct][0] + sc[ct][1]) + (sc[ct][2] + sc[ct][3]);
    }
    l_part += (rs4[0] + rs4[1]) + (rs4[2] + rs4[3]);

    // P stage: Pq[qrow][key] = P[key][qrow]; wave-private round-trip
#pragma unroll
    for (int ct = 0; ct < 4; ++ct) {
      bf16x4 pk;
#pragma unroll
      for (int r = 0; r < 4; ++r) pk[r] = (bf16)sc[ct][r];
      *(bf16x4*)(&Pq[wid][l16][ct * 16 + lhi * 4]) = pk;
    }
    bf16x8 pf0 = *(const bf16x8*)(&Pq[wid][l16][lhi * 8]);
    bf16x8 pf1 = *(const bf16x8*)(&Pq[wid][l16][32 + lhi * 8]);

    // PV: o[m=dh][n=qrow] += V^T x P ; A-frag from Vt[cur]
    __builtin_amdgcn_s_setprio(1);
#pragma unroll
    for (int dt = 0; dt < 4; ++dt) {
      bf16x8 vf0 = *(const bf16x8*)(&Vt[cur][dt * 16 + l16][lhi * 8]);
      bf16x8 vf1 = *(const bf16x8*)(&Vt[cur][dt * 16 + l16][32 + lhi * 8]);
      o[dt] = __builtin_amdgcn_mfma_f32_16x16x32_bf16(vf0, pf0, o[dt], 0, 0, 0);
      o[dt] = __builtin_amdgcn_mfma_f32_16x16x32_bf16(vf1, pf1, o[dt], 0, 0, 0);
    }
    __builtin_amdgcn_s_setprio(0);

    // single barrier: retires PV reads of Vt[cur], publishes Vt[cur^1]
    __syncthreads();
  }

  // epilogue: reduce l across the 4 lanes of the q-row, then normalize
  float l_i = l_part;
  l_i += __shfl_xor(l_i, 16);
  l_i += __shfl_xor(l_i, 32);
  float rl = 1.0f / l_i;
#pragma unroll
  for (int dt = 0; dt < 4; ++dt) {
    bf16x4 ok;
#pragma unroll
    for (int r = 0; r < 4; ++r) ok[r] = (bf16)(o[dt][r] * rl);
    *(bf16x4*)(&Pq[wid][l16][dt * 16 + lhi * 4]) = ok;
  }
  bf16x8 r0 = *(const bf16x8*)(&Pq[wid][l16][lhi * 16]);
  bf16x8 r1 = *(const bf16x8*)(&Pq[wid][l16][lhi * 16 + 8]);
  bf16* orow = qbase + (size_t)(q0 + l16) * D3 + lhi * 16;
  *(bf16x8*)(orow) = r0;
  *(bf16x8*)(orow + 8) = r1;
}

// ---------------------------------------------------------------------------
extern "C" void kernel_launch(void* const* d_in, const int* in_sizes, int n_in,
                              void* d_out, int out_size, void* d_ws,
                              size_t ws_size, hipStream_t stream) {
  constexpr int B = 4, S = 2048, D = 1024;

  const float* x = nullptr;
  const float* w_in = nullptr;
  const float* w_out = nullptr;
  const float* b_out = nullptr;
  for (int i = 0; i < n_in; ++i) {
    switch (in_sizes[i]) {
      case 8388608: x = (const float*)d_in[i]; break;
      case 3145728: w_in = (const float*)d_in[i]; break;
      case 1048576: w_out = (const float*)d_in[i]; break;
      case 1024: b_out = (const float*)d_in[i]; break;
    }
  }
  float* out = (float*)d_out;  // [4,2048,1024] fp32

  bf16* qkv = (bf16*)d_ws;
  const size_t need_full = (size_t)B * S * 3 * D * 2;  // 48 MiB

  if (ws_size >= need_full) {
    gemm_bt<float, bf16, false><<<dim3(3 * D / 128, B * S / 128), 256, 0,
                                  stream>>>(x, w_in, nullptr, qkv, B * S,
                                            3 * D, D, D, 0);
    attn_fwd<<<dim3(S / 64, B * 16), 256, 0, stream>>>(qkv);
    gemm_bt<bf16, float, true><<<dim3(D / 128, B * S / 128), 256, 0, stream>>>(
        qkv, w_out, b_out, out, B * S, D, D, 3 * D, 0);
  } else {
    for (int b0 = 0; b0 < B; ++b0) {
      gemm_bt<float, bf16, false><<<dim3(3 * D / 128, S / 128), 256, 0,
                                    stream>>>(x, w_in, nullptr, qkv, S, 3 * D,
                                              D, D, b0 * S);
      attn_fwd<<<dim3(S / 64, 16), 256, 0, stream>>>(qkv);
      gemm_bt<bf16, float, true><<<dim3(D / 128, S / 128), 256, 0, stream>>>(
          qkv, w_out, b_out, out + (size_t)b0 * S * D, S, D, D, 3 * D, 0);
    }
  }
}

// Round 5
// 376.432 us; speedup vs baseline: 1.4535x; 1.3652x over previous
//
#include <hip/hip_runtime.h>

typedef __bf16 bf16;
typedef __bf16 bf16x2 __attribute__((ext_vector_type(2)));
typedef __bf16 bf16x4 __attribute__((ext_vector_type(4)));
typedef __bf16 bf16x8 __attribute__((ext_vector_type(8)));
typedef float f32x4 __attribute__((ext_vector_type(4)));

// ---------------------------------------------------------------------------
// GEMM: C[M,N] = A[M,K] * B[N,K]^T (+bias), MFMA bf16, fp32 accumulate.
// (unchanged — proven)
// ---------------------------------------------------------------------------
template <typename TA, typename TC, bool ADD_BIAS>
__global__ __launch_bounds__(256) void gemm_bt(const TA* __restrict__ A,
                                               const float* __restrict__ B,
                                               const float* __restrict__ bias,
                                               TC* __restrict__ C,
                                               int M, int N, int K,
                                               int lda, int row0) {
  __shared__ __align__(16) bf16 As[128][72];
  __shared__ __align__(16) bf16 Bs[128][72];
  const int tid = threadIdx.x;
  const int lane = tid & 63;
  const int wid = tid >> 6;
  const int wr = wid >> 1, wc = wid & 1;
  const int m0 = blockIdx.y * 128;
  const int n0 = blockIdx.x * 128;
  const int l16 = lane & 15;
  const int lhi = lane >> 4;

  f32x4 acc[4][4] = {};

  for (int k0 = 0; k0 < K; k0 += 64) {
    __syncthreads();
#pragma unroll
    for (int p = 0; p < 8; ++p) {
      int v = tid + p * 256;
      int row = v >> 4;
      int kc = (v & 15) * 4;
      size_t ai = (size_t)(row0 + m0 + row) * lda + k0 + kc;
      size_t bi = (size_t)(n0 + row) * K + k0 + kc;
      bf16x4 ab, bb;
      if constexpr (__is_same(TA, float)) {
        f32x4 a4 = *(const f32x4*)((const float*)A + ai);
#pragma unroll
        for (int j = 0; j < 4; ++j) ab[j] = (bf16)a4[j];
      } else {
        ab = *(const bf16x4*)((const bf16*)A + ai);
      }
      f32x4 b4 = *(const f32x4*)(B + bi);
#pragma unroll
      for (int j = 0; j < 4; ++j) bb[j] = (bf16)b4[j];
      *(bf16x4*)(&As[row][kc]) = ab;
      *(bf16x4*)(&Bs[row][kc]) = bb;
    }
    __syncthreads();
#pragma unroll
    for (int ks = 0; ks < 2; ++ks) {
      bf16x8 af[4], bfr[4];
#pragma unroll
      for (int i = 0; i < 4; ++i) {
        af[i] = *(const bf16x8*)(&As[wr * 64 + i * 16 + l16][ks * 32 + lhi * 8]);
        bfr[i] = *(const bf16x8*)(&Bs[wc * 64 + i * 16 + l16][ks * 32 + lhi * 8]);
      }
#pragma unroll
      for (int i = 0; i < 4; ++i)
#pragma unroll
        for (int j = 0; j < 4; ++j)
          acc[i][j] = __builtin_amdgcn_mfma_f32_16x16x32_bf16(af[i], bfr[j],
                                                              acc[i][j], 0, 0, 0);
    }
  }

#pragma unroll
  for (int i = 0; i < 4; ++i) {
    int row_base = m0 + wr * 64 + i * 16 + lhi * 4;
#pragma unroll
    for (int j = 0; j < 4; ++j) {
      int col = n0 + wc * 64 + j * 16 + l16;
      float bv = ADD_BIAS ? bias[col] : 0.0f;
#pragma unroll
      for (int r = 0; r < 4; ++r) {
        float val = acc[i][j][r] + bv;
        if constexpr (__is_same(TC, float))
          C[(size_t)(row_base + r) * N + col] = val;
        else
          C[(size_t)(row_base + r) * N + col] = (bf16)val;
      }
    }
  }
}

// ---------------------------------------------------------------------------
// MFMA flash attention v7.
//  - NEW: K staged through LDS (double-buffered, like V). Previously each of
//    the 4 waves loaded the IDENTICAL 8 KB K-tile from global per tile (10
//    dependent VMEM loads/lane/tile, 4x redundant L2 traffic) — the last
//    untouched structure after r0-r4 falsified traffic/stride/shuffles/
//    barriers (dur pinned ~345us through all of them). Now: 4 VMEM loads/
//    lane/tile, K+V prefetched one full tile ahead, KQT reads are LDS hits.
//  - XCD swizzle, shuffle-free softmax (epilogue l-reduce), defer-max,
//    exp2-direct, setprio, single barrier/tile: all kept.
//  - LDS 46 KB -> 3 blocks/CU.
// ---------------------------------------------------------------------------
__global__ __launch_bounds__(256) void attn_fwd(bf16* __restrict__ qkv) {
  constexpr int S = 2048, D3 = 3072;
  constexpr float SCL = 0.18033688011112042f;  // 0.125 * log2(e)
  constexpr float THR = 11.5f;                 // 8 * log2(e), log2 domain
  __shared__ __align__(16) bf16 Kt[2][64][72];  // [buf][key][dim] row-major
  __shared__ __align__(16) bf16 Vt[2][64][72];  // [buf][dim][key] transposed
  __shared__ __align__(16) bf16 Pq[4][16][72];  // per-wave [qrow][key]

  const int tid = threadIdx.x;
  const int lane = tid & 63;
  const int wid = tid >> 6;
  const int l16 = lane & 15, lhi = lane >> 4;

  // XCD-aware bijective swizzle (nwg % 8 == 0 in both launch paths).
  const int nwg = gridDim.x * gridDim.y;        // 2048 (full) / 512 (fallback)
  const int bid = blockIdx.y * 32 + blockIdx.x; // gridDim.x == 32
  const int swz = (bid & 7) * (nwg >> 3) + (bid >> 3);
  const int bh = swz >> 5;                      // 32 q-tiles per bh
  const int b = bh >> 4, h = bh & 15;
  const int q0 = (swz & 31) * 64 + wid * 16;

  bf16* base = qkv + (size_t)b * S * D3;
  bf16* qbase = base + h * 64;
  const bf16* kbase = base + 1024 + h * 64;
  const bf16* vbase = base + 2048 + h * 64;

  // Q fragments, B-operand: n(qrow)=l16, k=lhi*8+j (cached before overwrite)
  bf16x8 qf[2];
#pragma unroll
  for (int ks = 0; ks < 2; ++ks)
    qf[ks] = *(const bf16x8*)(qbase + (size_t)(q0 + l16) * D3 + ks * 32 + lhi * 8);

  float m_i = -1e30f;    // running max, log2 domain, uniform per q-row
  float l_part = 0.0f;   // PER-LANE partial sum; reduced once in epilogue
  f32x4 o[4] = {};

  const int kp = tid & 31, oc = tid >> 5;  // thread stages keys 2kp,2kp+1, dims oc*8..+7

  // prologue: stage K(0), V(0) into buffer 0
  {
    bf16x8 k0 = *(const bf16x8*)(kbase + (size_t)(2 * kp) * D3 + oc * 8);
    bf16x8 k1 = *(const bf16x8*)(kbase + (size_t)(2 * kp + 1) * D3 + oc * 8);
    bf16x8 v0 = *(const bf16x8*)(vbase + (size_t)(2 * kp) * D3 + oc * 8);
    bf16x8 v1 = *(const bf16x8*)(vbase + (size_t)(2 * kp + 1) * D3 + oc * 8);
    *(bf16x8*)(&Kt[0][2 * kp][oc * 8]) = k0;
    *(bf16x8*)(&Kt[0][2 * kp + 1][oc * 8]) = k1;
#pragma unroll
    for (int j = 0; j < 8; ++j) {
      bf16x2 pr;
      pr[0] = v0[j];
      pr[1] = v1[j];
      *(bf16x2*)(&Vt[0][oc * 8 + j][2 * kp]) = pr;
    }
  }
  __syncthreads();

  for (int t = 0; t < S; t += 64) {
    const int cur = (t >> 6) & 1;
    const bool havenext = (t + 64 < S);

    // issue next tile's K+V global loads FIRST — hidden under KQT + softmax
    bf16x8 kn0, kn1, vn0, vn1;
    if (havenext) {
      const bf16* kb = kbase + (size_t)(t + 64) * D3;
      const bf16* vb = vbase + (size_t)(t + 64) * D3;
      kn0 = *(const bf16x8*)(kb + (size_t)(2 * kp) * D3 + oc * 8);
      kn1 = *(const bf16x8*)(kb + (size_t)(2 * kp + 1) * D3 + oc * 8);
      vn0 = *(const bf16x8*)(vb + (size_t)(2 * kp) * D3 + oc * 8);
      vn1 = *(const bf16x8*)(vb + (size_t)(2 * kp + 1) * D3 + oc * 8);
    }

    // K·Q^T from LDS: sc[ct][r] = score(key = t+ct*16+lhi*4+r, qrow = l16)
    f32x4 sc[4] = {};
    __builtin_amdgcn_s_setprio(1);
#pragma unroll
    for (int ct = 0; ct < 4; ++ct) {
#pragma unroll
      for (int ks = 0; ks < 2; ++ks) {
        bf16x8 kf = *(const bf16x8*)(&Kt[cur][ct * 16 + l16][ks * 32 + lhi * 8]);
        sc[ct] = __builtin_amdgcn_mfma_f32_16x16x32_bf16(kf, qf[ks], sc[ct], 0, 0, 0);
      }
    }
    __builtin_amdgcn_s_setprio(0);

    // in-lane max (16 keys) — no cross-lane ops in the common path
    float cm[4];
#pragma unroll
    for (int ct = 0; ct < 4; ++ct)
      cm[ct] = fmaxf(fmaxf(sc[ct][0], sc[ct][1]), fmaxf(sc[ct][2], sc[ct][3]));
    float mxs = fmaxf(fmaxf(cm[0], cm[1]), fmaxf(cm[2], cm[3])) * SCL;

    // defer-max: rescale only if some lane's tile max exceeds m_i + THR
    if (!__all(mxs - m_i <= THR)) {
      float mw = mxs;
      mw = fmaxf(mw, __shfl_xor(mw, 16));
      mw = fmaxf(mw, __shfl_xor(mw, 32));
      float nm = fmaxf(m_i, mw);
      float alpha = __builtin_amdgcn_exp2f(m_i - nm);
      m_i = nm;
      l_part *= alpha;
#pragma unroll
      for (int dt = 0; dt < 4; ++dt)
#pragma unroll
        for (int r = 0; r < 4; ++r) o[dt][r] *= alpha;
    }

    // stage K(t+1), V(t+1) into the other buffer (published by end barrier)
    if (havenext) {
      *(bf16x8*)(&Kt[cur ^ 1][2 * kp][oc * 8]) = kn0;
      *(bf16x8*)(&Kt[cur ^ 1][2 * kp + 1][oc * 8]) = kn1;
#pragma unroll
      for (int j = 0; j < 8; ++j) {
        bf16x2 pr;
        pr[0] = vn0[j];
        pr[1] = vn1[j];
        *(bf16x2*)(&Vt[cur ^ 1][oc * 8 + j][2 * kp]) = pr;
      }
    }

    // P = exp2(s*SCL - m_i); per-lane partial sum (no reduce)
    float rs4[4];
#pragma unroll
    for (int ct = 0; ct < 4; ++ct) {
#pragma unroll
      for (int r = 0; r < 4; ++r) {
        float p = __builtin_amdgcn_exp2f(__builtin_fmaf(sc[ct][r], SCL, -m_i));
        sc[ct][r] = p;
      }
      rs4[ct] = (sc[ct][0] + sc[ct][1]) + (sc[ct][2] + sc[ct][3]);
    }
    l_part += (rs4[0] + rs4[1]) + (rs4[2] + rs4[3]);

    // P stage: Pq[qrow][key] = P[key][qrow]; wave-private round-trip
#pragma unroll
    for (int ct = 0; ct < 4; ++ct) {
      bf16x4 pk;
#pragma unroll
      for (int r = 0; r < 4; ++r) pk[r] = (bf16)sc[ct][r];
      *(bf16x4*)(&Pq[wid][l16][ct * 16 + lhi * 4]) = pk;
    }
    bf16x8 pf0 = *(const bf16x8*)(&Pq[wid][l16][lhi * 8]);
    bf16x8 pf1 = *(const bf16x8*)(&Pq[wid][l16][32 + lhi * 8]);

    // PV: o[m=dh][n=qrow] += V^T x P ; A-frag from Vt[cur]
    __builtin_amdgcn_s_setprio(1);
#pragma unroll
    for (int dt = 0; dt < 4; ++dt) {
      bf16x8 vf0 = *(const bf16x8*)(&Vt[cur][dt * 16 + l16][lhi * 8]);
      bf16x8 vf1 = *(const bf16x8*)(&Vt[cur][dt * 16 + l16][32 + lhi * 8]);
      o[dt] = __builtin_amdgcn_mfma_f32_16x16x32_bf16(vf0, pf0, o[dt], 0, 0, 0);
      o[dt] = __builtin_amdgcn_mfma_f32_16x16x32_bf16(vf1, pf1, o[dt], 0, 0, 0);
    }
    __builtin_amdgcn_s_setprio(0);

    // single barrier: retires this tile's LDS reads, publishes buffer cur^1
    __syncthreads();
  }

  // epilogue: reduce l across the 4 lanes of the q-row, then normalize
  float l_i = l_part;
  l_i += __shfl_xor(l_i, 16);
  l_i += __shfl_xor(l_i, 32);
  float rl = 1.0f / l_i;
#pragma unroll
  for (int dt = 0; dt < 4; ++dt) {
    bf16x4 ok;
#pragma unroll
    for (int r = 0; r < 4; ++r) ok[r] = (bf16)(o[dt][r] * rl);
    *(bf16x4*)(&Pq[wid][l16][dt * 16 + lhi * 4]) = ok;
  }
  bf16x8 r0 = *(const bf16x8*)(&Pq[wid][l16][lhi * 16]);
  bf16x8 r1 = *(const bf16x8*)(&Pq[wid][l16][lhi * 16 + 8]);
  bf16* orow = qbase + (size_t)(q0 + l16) * D3 + lhi * 16;
  *(bf16x8*)(orow) = r0;
  *(bf16x8*)(orow + 8) = r1;
}

// ---------------------------------------------------------------------------
extern "C" void kernel_launch(void* const* d_in, const int* in_sizes, int n_in,
                              void* d_out, int out_size, void* d_ws,
                              size_t ws_size, hipStream_t stream) {
  constexpr int B = 4, S = 2048, D = 1024;

  const float* x = nullptr;
  const float* w_in = nullptr;
  const float* w_out = nullptr;
  const float* b_out = nullptr;
  for (int i = 0; i < n_in; ++i) {
    switch (in_sizes[i]) {
      case 8388608: x = (const float*)d_in[i]; break;
      case 3145728: w_in = (const float*)d_in[i]; break;
      case 1048576: w_out = (const float*)d_in[i]; break;
      case 1024: b_out = (const float*)d_in[i]; break;
    }
  }
  float* out = (float*)d_out;  // [4,2048,1024] fp32

  bf16* qkv = (bf16*)d_ws;
  const size_t need_full = (size_t)B * S * 3 * D * 2;  // 48 MiB

  if (ws_size >= need_full) {
    gemm_bt<float, bf16, false><<<dim3(3 * D / 128, B * S / 128), 256, 0,
                                  stream>>>(x, w_in, nullptr, qkv, B * S,
                                            3 * D, D, D, 0);
    attn_fwd<<<dim3(S / 64, B * 16), 256, 0, stream>>>(qkv);
    gemm_bt<bf16, float, true><<<dim3(D / 128, B * S / 128), 256, 0, stream>>>(
        qkv, w_out, b_out, out, B * S, D, D, 3 * D, 0);
  } else {
    for (int b0 = 0; b0 < B; ++b0) {
      gemm_bt<float, bf16, false><<<dim3(3 * D / 128, S / 128), 256, 0,
                                    stream>>>(x, w_in, nullptr, qkv, S, 3 * D,
                                              D, D, b0 * S);
      attn_fwd<<<dim3(S / 64, 16), 256, 0, stream>>>(qkv);
      gemm_bt<bf16, float, true><<<dim3(D / 128, S / 128), 256, 0, stream>>>(
          qkv, w_out, b_out, out + (size_t)b0 * S * D, S, D, D, 3 * D, 0);
    }
  }
}

// Round 6
// 356.103 us; speedup vs baseline: 1.5365x; 1.0571x over previous
//
#include <hip/hip_runtime.h>

typedef __bf16 bf16;
typedef __bf16 bf16x2 __attribute__((ext_vector_type(2)));
typedef __bf16 bf16x4 __attribute__((ext_vector_type(4)));
typedef __bf16 bf16x8 __attribute__((ext_vector_type(8)));
typedef float f32x4 __attribute__((ext_vector_type(4)));

typedef __attribute__((address_space(1))) const unsigned int gq_t;
typedef __attribute__((address_space(3))) unsigned int lq_t;

// ---------------------------------------------------------------------------
// fp32 -> bf16 converter, 8 elems/thread (f32x4 x2 -> bf16x8).
// ---------------------------------------------------------------------------
__global__ __launch_bounds__(256) void cvt_bf16(const float* __restrict__ in,
                                                bf16* __restrict__ out,
                                                int n8) {
  int i = blockIdx.x * 256 + threadIdx.x;
  if (i >= n8) return;
  f32x4 a = ((const f32x4*)in)[2 * i];
  f32x4 b = ((const f32x4*)in)[2 * i + 1];
  bf16x8 o;
#pragma unroll
  for (int j = 0; j < 4; ++j) {
    o[j] = (bf16)a[j];
    o[4 + j] = (bf16)b[j];
  }
  ((bf16x8*)out)[i] = o;
}

// ---------------------------------------------------------------------------
// bf16 GEMM with global_load_lds width-16 staging (m97 structure, the proven
// 517->874 TF rung). C[M,N] = A[M,K](lda) * B[N,K]^T (+bias).
// LDS linear [128][64] per operand (glds needs wave-uniform base + lane*16
// linear dest). 128x128 tile, BK=64, 4 waves, 2 barriers/K-step.
// ---------------------------------------------------------------------------
template <typename TC, bool ADD_BIAS>
__global__ __launch_bounds__(256) void gemm_glds(const bf16* __restrict__ A,
                                                 const bf16* __restrict__ B,
                                                 const float* __restrict__ bias,
                                                 TC* __restrict__ C,
                                                 int M, int N, int K, int lda) {
  __shared__ __align__(16) bf16 As[128 * 64];
  __shared__ __align__(16) bf16 Bs[128 * 64];
  const int tid = threadIdx.x;
  const int lane = tid & 63;
  const int wid = tid >> 6;
  const int wr = wid >> 1, wc = wid & 1;
  const int m0 = blockIdx.y * 128;
  const int n0 = blockIdx.x * 128;
  const int l16 = lane & 15;
  const int lhi = lane >> 4;
  const int lr = lane >> 3;       // row within 8-row chunk
  const int lc = (lane & 7) * 8;  // col (elems) within row

  f32x4 acc[4][4] = {};

  for (int k0 = 0; k0 < K; k0 += 64) {
    __syncthreads();
#pragma unroll
    for (int i = 0; i < 4; ++i) {
      const int chunk = wid * 4 + i;  // 16 chunks of 8 rows x 64 cols
      const int row = chunk * 8 + lr;
      const bf16* ga = A + (size_t)(m0 + row) * lda + k0 + lc;
      const bf16* gb = B + (size_t)(n0 + row) * K + k0 + lc;
      __builtin_amdgcn_global_load_lds((gq_t*)ga, (lq_t*)&As[chunk * 512], 16,
                                       0, 0);
      __builtin_amdgcn_global_load_lds((gq_t*)gb, (lq_t*)&Bs[chunk * 512], 16,
                                       0, 0);
    }
    __syncthreads();
#pragma unroll
    for (int ks = 0; ks < 2; ++ks) {
      bf16x8 af[4], bfr[4];
#pragma unroll
      for (int i = 0; i < 4; ++i) {
        af[i] = *(const bf16x8*)(&As[(wr * 64 + i * 16 + l16) * 64 + ks * 32 +
                                     lhi * 8]);
        bfr[i] = *(const bf16x8*)(&Bs[(wc * 64 + i * 16 + l16) * 64 + ks * 32 +
                                      lhi * 8]);
      }
#pragma unroll
      for (int i = 0; i < 4; ++i)
#pragma unroll
        for (int j = 0; j < 4; ++j)
          acc[i][j] = __builtin_amdgcn_mfma_f32_16x16x32_bf16(af[i], bfr[j],
                                                              acc[i][j], 0, 0, 0);
    }
  }

#pragma unroll
  for (int i = 0; i < 4; ++i) {
    int row_base = m0 + wr * 64 + i * 16 + lhi * 4;
#pragma unroll
    for (int j = 0; j < 4; ++j) {
      int col = n0 + wc * 64 + j * 16 + l16;
      float bv = ADD_BIAS ? bias[col] : 0.0f;
#pragma unroll
      for (int r = 0; r < 4; ++r) {
        float val = acc[i][j][r] + bv;
        if constexpr (__is_same(TC, float))
          C[(size_t)(row_base + r) * N + col] = val;
        else
          C[(size_t)(row_base + r) * N + col] = (bf16)val;
      }
    }
  }
}

// ---------------------------------------------------------------------------
// GEMM (legacy reg-staged, fp32 B): kept for the low-workspace fallback paths.
// ---------------------------------------------------------------------------
template <typename TA, typename TC, bool ADD_BIAS>
__global__ __launch_bounds__(256) void gemm_bt(const TA* __restrict__ A,
                                               const float* __restrict__ B,
                                               const float* __restrict__ bias,
                                               TC* __restrict__ C,
                                               int M, int N, int K,
                                               int lda, int row0) {
  __shared__ __align__(16) bf16 As[128][72];
  __shared__ __align__(16) bf16 Bs[128][72];
  const int tid = threadIdx.x;
  const int lane = tid & 63;
  const int wid = tid >> 6;
  const int wr = wid >> 1, wc = wid & 1;
  const int m0 = blockIdx.y * 128;
  const int n0 = blockIdx.x * 128;
  const int l16 = lane & 15;
  const int lhi = lane >> 4;

  f32x4 acc[4][4] = {};

  for (int k0 = 0; k0 < K; k0 += 64) {
    __syncthreads();
#pragma unroll
    for (int p = 0; p < 8; ++p) {
      int v = tid + p * 256;
      int row = v >> 4;
      int kc = (v & 15) * 4;
      size_t ai = (size_t)(row0 + m0 + row) * lda + k0 + kc;
      size_t bi = (size_t)(n0 + row) * K + k0 + kc;
      bf16x4 ab, bb;
      if constexpr (__is_same(TA, float)) {
        f32x4 a4 = *(const f32x4*)((const float*)A + ai);
#pragma unroll
        for (int j = 0; j < 4; ++j) ab[j] = (bf16)a4[j];
      } else {
        ab = *(const bf16x4*)((const bf16*)A + ai);
      }
      f32x4 b4 = *(const f32x4*)(B + bi);
#pragma unroll
      for (int j = 0; j < 4; ++j) bb[j] = (bf16)b4[j];
      *(bf16x4*)(&As[row][kc]) = ab;
      *(bf16x4*)(&Bs[row][kc]) = bb;
    }
    __syncthreads();
#pragma unroll
    for (int ks = 0; ks < 2; ++ks) {
      bf16x8 af[4], bfr[4];
#pragma unroll
      for (int i = 0; i < 4; ++i) {
        af[i] = *(const bf16x8*)(&As[wr * 64 + i * 16 + l16][ks * 32 + lhi * 8]);
        bfr[i] = *(const bf16x8*)(&Bs[wc * 64 + i * 16 + l16][ks * 32 + lhi * 8]);
      }
#pragma unroll
      for (int i = 0; i < 4; ++i)
#pragma unroll
        for (int j = 0; j < 4; ++j)
          acc[i][j] = __builtin_amdgcn_mfma_f32_16x16x32_bf16(af[i], bfr[j],
                                                              acc[i][j], 0, 0, 0);
    }
  }

#pragma unroll
  for (int i = 0; i < 4; ++i) {
    int row_base = m0 + wr * 64 + i * 16 + lhi * 4;
#pragma unroll
    for (int j = 0; j < 4; ++j) {
      int col = n0 + wc * 64 + j * 16 + l16;
      float bv = ADD_BIAS ? bias[col] : 0.0f;
#pragma unroll
      for (int r = 0; r < 4; ++r) {
        float val = acc[i][j][r] + bv;
        if constexpr (__is_same(TC, float))
          C[(size_t)(row_base + r) * N + col] = val;
        else
          C[(size_t)(row_base + r) * N + col] = (bf16)val;
      }
    }
  }
}

// ---------------------------------------------------------------------------
// MFMA flash attention v7 (unchanged — round-5 proven: 345 -> 180 us).
// K+V double-buffered through LDS, prefetch 1 tile ahead; XCD swizzle;
// shuffle-free softmax common path; defer-max; exp2-direct; setprio.
// ---------------------------------------------------------------------------
__global__ __launch_bounds__(256) void attn_fwd(bf16* __restrict__ qkv) {
  constexpr int S = 2048, D3 = 3072;
  constexpr float SCL = 0.18033688011112042f;  // 0.125 * log2(e)
  constexpr float THR = 11.5f;                 // 8 * log2(e), log2 domain
  __shared__ __align__(16) bf16 Kt[2][64][72];  // [buf][key][dim] row-major
  __shared__ __align__(16) bf16 Vt[2][64][72];  // [buf][dim][key] transposed
  __shared__ __align__(16) bf16 Pq[4][16][72];  // per-wave [qrow][key]

  const int tid = threadIdx.x;
  const int lane = tid & 63;
  const int wid = tid >> 6;
  const int l16 = lane & 15, lhi = lane >> 4;

  // XCD-aware bijective swizzle (nwg % 8 == 0 in both launch paths).
  const int nwg = gridDim.x * gridDim.y;        // 2048 (full) / 512 (fallback)
  const int bid = blockIdx.y * 32 + blockIdx.x; // gridDim.x == 32
  const int swz = (bid & 7) * (nwg >> 3) + (bid >> 3);
  const int bh = swz >> 5;                      // 32 q-tiles per bh
  const int b = bh >> 4, h = bh & 15;
  const int q0 = (swz & 31) * 64 + wid * 16;

  bf16* base = qkv + (size_t)b * S * D3;
  bf16* qbase = base + h * 64;
  const bf16* kbase = base + 1024 + h * 64;
  const bf16* vbase = base + 2048 + h * 64;

  // Q fragments, B-operand: n(qrow)=l16, k=lhi*8+j (cached before overwrite)
  bf16x8 qf[2];
#pragma unroll
  for (int ks = 0; ks < 2; ++ks)
    qf[ks] = *(const bf16x8*)(qbase + (size_t)(q0 + l16) * D3 + ks * 32 + lhi * 8);

  float m_i = -1e30f;    // running max, log2 domain, uniform per q-row
  float l_part = 0.0f;   // PER-LANE partial sum; reduced once in epilogue
  f32x4 o[4] = {};

  const int kp = tid & 31, oc = tid >> 5;  // stages keys 2kp,2kp+1, dims oc*8..+7

  // prologue: stage K(0), V(0) into buffer 0
  {
    bf16x8 k0 = *(const bf16x8*)(kbase + (size_t)(2 * kp) * D3 + oc * 8);
    bf16x8 k1 = *(const bf16x8*)(kbase + (size_t)(2 * kp + 1) * D3 + oc * 8);
    bf16x8 v0 = *(const bf16x8*)(vbase + (size_t)(2 * kp) * D3 + oc * 8);
    bf16x8 v1 = *(const bf16x8*)(vbase + (size_t)(2 * kp + 1) * D3 + oc * 8);
    *(bf16x8*)(&Kt[0][2 * kp][oc * 8]) = k0;
    *(bf16x8*)(&Kt[0][2 * kp + 1][oc * 8]) = k1;
#pragma unroll
    for (int j = 0; j < 8; ++j) {
      bf16x2 pr;
      pr[0] = v0[j];
      pr[1] = v1[j];
      *(bf16x2*)(&Vt[0][oc * 8 + j][2 * kp]) = pr;
    }
  }
  __syncthreads();

  for (int t = 0; t < S; t += 64) {
    const int cur = (t >> 6) & 1;
    const bool havenext = (t + 64 < S);

    // issue next tile's K+V global loads FIRST — hidden under KQT + softmax
    bf16x8 kn0, kn1, vn0, vn1;
    if (havenext) {
      const bf16* kb = kbase + (size_t)(t + 64) * D3;
      const bf16* vb = vbase + (size_t)(t + 64) * D3;
      kn0 = *(const bf16x8*)(kb + (size_t)(2 * kp) * D3 + oc * 8);
      kn1 = *(const bf16x8*)(kb + (size_t)(2 * kp + 1) * D3 + oc * 8);
      vn0 = *(const bf16x8*)(vb + (size_t)(2 * kp) * D3 + oc * 8);
      vn1 = *(const bf16x8*)(vb + (size_t)(2 * kp + 1) * D3 + oc * 8);
    }

    // K·Q^T from LDS: sc[ct][r] = score(key = t+ct*16+lhi*4+r, qrow = l16)
    f32x4 sc[4] = {};
    __builtin_amdgcn_s_setprio(1);
#pragma unroll
    for (int ct = 0; ct < 4; ++ct) {
#pragma unroll
      for (int ks = 0; ks < 2; ++ks) {
        bf16x8 kf = *(const bf16x8*)(&Kt[cur][ct * 16 + l16][ks * 32 + lhi * 8]);
        sc[ct] = __builtin_amdgcn_mfma_f32_16x16x32_bf16(kf, qf[ks], sc[ct], 0, 0, 0);
      }
    }
    __builtin_amdgcn_s_setprio(0);

    // in-lane max (16 keys) — no cross-lane ops in the common path
    float cm[4];
#pragma unroll
    for (int ct = 0; ct < 4; ++ct)
      cm[ct] = fmaxf(fmaxf(sc[ct][0], sc[ct][1]), fmaxf(sc[ct][2], sc[ct][3]));
    float mxs = fmaxf(fmaxf(cm[0], cm[1]), fmaxf(cm[2], cm[3])) * SCL;

    // defer-max: rescale only if some lane's tile max exceeds m_i + THR
    if (!__all(mxs - m_i <= THR)) {
      float mw = mxs;
      mw = fmaxf(mw, __shfl_xor(mw, 16));
      mw = fmaxf(mw, __shfl_xor(mw, 32));
      float nm = fmaxf(m_i, mw);
      float alpha = __builtin_amdgcn_exp2f(m_i - nm);
      m_i = nm;
      l_part *= alpha;
#pragma unroll
      for (int dt = 0; dt < 4; ++dt)
#pragma unroll
        for (int r = 0; r < 4; ++r) o[dt][r] *= alpha;
    }

    // stage K(t+1), V(t+1) into the other buffer (published by end barrier)
    if (havenext) {
      *(bf16x8*)(&Kt[cur ^ 1][2 * kp][oc * 8]) = kn0;
      *(bf16x8*)(&Kt[cur ^ 1][2 * kp + 1][oc * 8]) = kn1;
#pragma unroll
      for (int j = 0; j < 8; ++j) {
        bf16x2 pr;
        pr[0] = vn0[j];
        pr[1] = vn1[j];
        *(bf16x2*)(&Vt[cur ^ 1][oc * 8 + j][2 * kp]) = pr;
      }
    }

    // P = exp2(s*SCL - m_i); per-lane partial sum (no reduce)
    float rs4[4];
#pragma unroll
    for (int ct = 0; ct < 4; ++ct) {
#pragma unroll
      for (int r = 0; r < 4; ++r) {
        float p = __builtin_amdgcn_exp2f(__builtin_fmaf(sc[ct][r], SCL, -m_i));
        sc[ct][r] = p;
      }
      rs4[ct] = (sc[ct][0] + sc[ct][1]) + (sc[ct][2] + sc[ct][3]);
    }
    l_part += (rs4[0] + rs4[1]) + (rs4[2] + rs4[3]);

    // P stage: Pq[qrow][key] = P[key][qrow]; wave-private round-trip
#pragma unroll
    for (int ct = 0; ct < 4; ++ct) {
      bf16x4 pk;
#pragma unroll
      for (int r = 0; r < 4; ++r) pk[r] = (bf16)sc[ct][r];
      *(bf16x4*)(&Pq[wid][l16][ct * 16 + lhi * 4]) = pk;
    }
    bf16x8 pf0 = *(const bf16x8*)(&Pq[wid][l16][lhi * 8]);
    bf16x8 pf1 = *(const bf16x8*)(&Pq[wid][l16][32 + lhi * 8]);

    // PV: o[m=dh][n=qrow] += V^T x P ; A-frag from Vt[cur]
    __builtin_amdgcn_s_setprio(1);
#pragma unroll
    for (int dt = 0; dt < 4; ++dt) {
      bf16x8 vf0 = *(const bf16x8*)(&Vt[cur][dt * 16 + l16][lhi * 8]);
      bf16x8 vf1 = *(const bf16x8*)(&Vt[cur][dt * 16 + l16][32 + lhi * 8]);
      o[dt] = __builtin_amdgcn_mfma_f32_16x16x32_bf16(vf0, pf0, o[dt], 0, 0, 0);
      o[dt] = __builtin_amdgcn_mfma_f32_16x16x32_bf16(vf1, pf1, o[dt], 0, 0, 0);
    }
    __builtin_amdgcn_s_setprio(0);

    // single barrier: retires this tile's LDS reads, publishes buffer cur^1
    __syncthreads();
  }

  // epilogue: reduce l across the 4 lanes of the q-row, then normalize
  float l_i = l_part;
  l_i += __shfl_xor(l_i, 16);
  l_i += __shfl_xor(l_i, 32);
  float rl = 1.0f / l_i;
#pragma unroll
  for (int dt = 0; dt < 4; ++dt) {
    bf16x4 ok;
#pragma unroll
    for (int r = 0; r < 4; ++r) ok[r] = (bf16)(o[dt][r] * rl);
    *(bf16x4*)(&Pq[wid][l16][dt * 16 + lhi * 4]) = ok;
  }
  bf16x8 r0 = *(const bf16x8*)(&Pq[wid][l16][lhi * 16]);
  bf16x8 r1 = *(const bf16x8*)(&Pq[wid][l16][lhi * 16 + 8]);
  bf16* orow = qbase + (size_t)(q0 + l16) * D3 + lhi * 16;
  *(bf16x8*)(orow) = r0;
  *(bf16x8*)(orow + 8) = r1;
}

// ---------------------------------------------------------------------------
extern "C" void kernel_launch(void* const* d_in, const int* in_sizes, int n_in,
                              void* d_out, int out_size, void* d_ws,
                              size_t ws_size, hipStream_t stream) {
  constexpr int B = 4, S = 2048, D = 1024;

  const float* x = nullptr;
  const float* w_in = nullptr;
  const float* w_out = nullptr;
  const float* b_out = nullptr;
  for (int i = 0; i < n_in; ++i) {
    switch (in_sizes[i]) {
      case 8388608: x = (const float*)d_in[i]; break;
      case 3145728: w_in = (const float*)d_in[i]; break;
      case 1048576: w_out = (const float*)d_in[i]; break;
      case 1024: b_out = (const float*)d_in[i]; break;
    }
  }
  float* out = (float*)d_out;  // [4,2048,1024] fp32

  bf16* qkv = (bf16*)d_ws;
  const size_t need_full = (size_t)B * S * 3 * D * 2;      // 48 MiB (qkv)
  const size_t need_cvt = need_full +
                          ((size_t)B * S * D +              // x  bf16: 16 MiB
                           (size_t)3 * D * D +              // w_in bf16: 6 MiB
                           (size_t)D * D) * 2;              // w_out bf16: 2 MiB

  if (ws_size >= need_cvt) {
    bf16* xb = qkv + (size_t)B * S * 3 * D;
    bf16* w_inb = xb + (size_t)B * S * D;
    bf16* w_outb = w_inb + (size_t)3 * D * D;
    const int nx8 = B * S * D / 8;       // 1048576
    const int nwi8 = 3 * D * D / 8;      // 393216
    const int nwo8 = D * D / 8;          // 131072
    cvt_bf16<<<dim3((nx8 + 255) / 256), 256, 0, stream>>>(x, xb, nx8);
    cvt_bf16<<<dim3((nwi8 + 255) / 256), 256, 0, stream>>>(w_in, w_inb, nwi8);
    cvt_bf16<<<dim3((nwo8 + 255) / 256), 256, 0, stream>>>(w_out, w_outb, nwo8);

    gemm_glds<bf16, false><<<dim3(3 * D / 128, B * S / 128), 256, 0, stream>>>(
        xb, w_inb, nullptr, qkv, B * S, 3 * D, D, D);
    attn_fwd<<<dim3(S / 64, B * 16), 256, 0, stream>>>(qkv);
    gemm_glds<float, true><<<dim3(D / 128, B * S / 128), 256, 0, stream>>>(
        qkv, w_outb, b_out, out, B * S, D, D, 3 * D);
  } else if (ws_size >= need_full) {
    gemm_bt<float, bf16, false><<<dim3(3 * D / 128, B * S / 128), 256, 0,
                                  stream>>>(x, w_in, nullptr, qkv, B * S,
                                            3 * D, D, D, 0);
    attn_fwd<<<dim3(S / 64, B * 16), 256, 0, stream>>>(qkv);
    gemm_bt<bf16, float, true><<<dim3(D / 128, B * S / 128), 256, 0, stream>>>(
        qkv, w_out, b_out, out, B * S, D, D, 3 * D, 0);
  } else {
    for (int b0 = 0; b0 < B; ++b0) {
      gemm_bt<float, bf16, false><<<dim3(3 * D / 128, S / 128), 256, 0,
                                    stream>>>(x, w_in, nullptr, qkv, S, 3 * D,
                                              D, D, b0 * S);
      attn_fwd<<<dim3(S / 64, 16), 256, 0, stream>>>(qkv);
      gemm_bt<bf16, float, true><<<dim3(D / 128, S / 128), 256, 0, stream>>>(
          qkv, w_out, b_out, out + (size_t)b0 * S * D, S, D, D, 3 * D, 0);
    }
  }
}

// Round 7
// 328.197 us; speedup vs baseline: 1.6671x; 1.0850x over previous
//
#include <hip/hip_runtime.h>

typedef __bf16 bf16;
typedef __bf16 bf16x2 __attribute__((ext_vector_type(2)));
typedef __bf16 bf16x4 __attribute__((ext_vector_type(4)));
typedef __bf16 bf16x8 __attribute__((ext_vector_type(8)));
typedef float f32x4 __attribute__((ext_vector_type(4)));

typedef __attribute__((address_space(1))) const unsigned int gq_t;
typedef __attribute__((address_space(3))) unsigned int lq_t;

// ---------------------------------------------------------------------------
// fp32 -> bf16 converter, 8 elems/thread.
// ---------------------------------------------------------------------------
__global__ __launch_bounds__(256) void cvt_bf16(const float* __restrict__ in,
                                                bf16* __restrict__ out,
                                                int n8) {
  int i = blockIdx.x * 256 + threadIdx.x;
  if (i >= n8) return;
  f32x4 a = ((const f32x4*)in)[2 * i];
  f32x4 b = ((const f32x4*)in)[2 * i + 1];
  bf16x8 o;
#pragma unroll
  for (int j = 0; j < 4; ++j) {
    o[j] = (bf16)a[j];
    o[4 + j] = (bf16)b[j];
  }
  ((bf16x8*)out)[i] = o;
}

// ---------------------------------------------------------------------------
// bf16 GEMM, global_load_lds width-16 staging (round-6, kept).
// ---------------------------------------------------------------------------
template <typename TC, bool ADD_BIAS>
__global__ __launch_bounds__(256) void gemm_glds(const bf16* __restrict__ A,
                                                 const bf16* __restrict__ B,
                                                 const float* __restrict__ bias,
                                                 TC* __restrict__ C,
                                                 int M, int N, int K, int lda) {
  __shared__ __align__(16) bf16 As[128 * 64];
  __shared__ __align__(16) bf16 Bs[128 * 64];
  const int tid = threadIdx.x;
  const int lane = tid & 63;
  const int wid = tid >> 6;
  const int wr = wid >> 1, wc = wid & 1;
  const int m0 = blockIdx.y * 128;
  const int n0 = blockIdx.x * 128;
  const int l16 = lane & 15;
  const int lhi = lane >> 4;
  const int lr = lane >> 3;
  const int lc = (lane & 7) * 8;

  f32x4 acc[4][4] = {};

  for (int k0 = 0; k0 < K; k0 += 64) {
    __syncthreads();
#pragma unroll
    for (int i = 0; i < 4; ++i) {
      const int chunk = wid * 4 + i;
      const int row = chunk * 8 + lr;
      const bf16* ga = A + (size_t)(m0 + row) * lda + k0 + lc;
      const bf16* gb = B + (size_t)(n0 + row) * K + k0 + lc;
      __builtin_amdgcn_global_load_lds((gq_t*)ga, (lq_t*)&As[chunk * 512], 16,
                                       0, 0);
      __builtin_amdgcn_global_load_lds((gq_t*)gb, (lq_t*)&Bs[chunk * 512], 16,
                                       0, 0);
    }
    __syncthreads();
#pragma unroll
    for (int ks = 0; ks < 2; ++ks) {
      bf16x8 af[4], bfr[4];
#pragma unroll
      for (int i = 0; i < 4; ++i) {
        af[i] = *(const bf16x8*)(&As[(wr * 64 + i * 16 + l16) * 64 + ks * 32 +
                                     lhi * 8]);
        bfr[i] = *(const bf16x8*)(&Bs[(wc * 64 + i * 16 + l16) * 64 + ks * 32 +
                                      lhi * 8]);
      }
#pragma unroll
      for (int i = 0; i < 4; ++i)
#pragma unroll
        for (int j = 0; j < 4; ++j)
          acc[i][j] = __builtin_amdgcn_mfma_f32_16x16x32_bf16(af[i], bfr[j],
                                                              acc[i][j], 0, 0, 0);
    }
  }

#pragma unroll
  for (int i = 0; i < 4; ++i) {
    int row_base = m0 + wr * 64 + i * 16 + lhi * 4;
#pragma unroll
    for (int j = 0; j < 4; ++j) {
      int col = n0 + wc * 64 + j * 16 + l16;
      float bv = ADD_BIAS ? bias[col] : 0.0f;
#pragma unroll
      for (int r = 0; r < 4; ++r) {
        float val = acc[i][j][r] + bv;
        if constexpr (__is_same(TC, float))
          C[(size_t)(row_base + r) * N + col] = val;
        else
          C[(size_t)(row_base + r) * N + col] = (bf16)val;
      }
    }
  }
}

// ---------------------------------------------------------------------------
// GEMM (legacy reg-staged, fp32 B): low-workspace fallback only.
// ---------------------------------------------------------------------------
template <typename TA, typename TC, bool ADD_BIAS>
__global__ __launch_bounds__(256) void gemm_bt(const TA* __restrict__ A,
                                               const float* __restrict__ B,
                                               const float* __restrict__ bias,
                                               TC* __restrict__ C,
                                               int M, int N, int K,
                                               int lda, int row0) {
  __shared__ __align__(16) bf16 As[128][72];
  __shared__ __align__(16) bf16 Bs[128][72];
  const int tid = threadIdx.x;
  const int lane = tid & 63;
  const int wid = tid >> 6;
  const int wr = wid >> 1, wc = wid & 1;
  const int m0 = blockIdx.y * 128;
  const int n0 = blockIdx.x * 128;
  const int l16 = lane & 15;
  const int lhi = lane >> 4;

  f32x4 acc[4][4] = {};

  for (int k0 = 0; k0 < K; k0 += 64) {
    __syncthreads();
#pragma unroll
    for (int p = 0; p < 8; ++p) {
      int v = tid + p * 256;
      int row = v >> 4;
      int kc = (v & 15) * 4;
      size_t ai = (size_t)(row0 + m0 + row) * lda + k0 + kc;
      size_t bi = (size_t)(n0 + row) * K + k0 + kc;
      bf16x4 ab, bb;
      if constexpr (__is_same(TA, float)) {
        f32x4 a4 = *(const f32x4*)((const float*)A + ai);
#pragma unroll
        for (int j = 0; j < 4; ++j) ab[j] = (bf16)a4[j];
      } else {
        ab = *(const bf16x4*)((const bf16*)A + ai);
      }
      f32x4 b4 = *(const f32x4*)(B + bi);
#pragma unroll
      for (int j = 0; j < 4; ++j) bb[j] = (bf16)b4[j];
      *(bf16x4*)(&As[row][kc]) = ab;
      *(bf16x4*)(&Bs[row][kc]) = bb;
    }
    __syncthreads();
#pragma unroll
    for (int ks = 0; ks < 2; ++ks) {
      bf16x8 af[4], bfr[4];
#pragma unroll
      for (int i = 0; i < 4; ++i) {
        af[i] = *(const bf16x8*)(&As[wr * 64 + i * 16 + l16][ks * 32 + lhi * 8]);
        bfr[i] = *(const bf16x8*)(&Bs[wc * 64 + i * 16 + l16][ks * 32 + lhi * 8]);
      }
#pragma unroll
      for (int i = 0; i < 4; ++i)
#pragma unroll
        for (int j = 0; j < 4; ++j)
          acc[i][j] = __builtin_amdgcn_mfma_f32_16x16x32_bf16(af[i], bfr[j],
                                                              acc[i][j], 0, 0, 0);
    }
  }

#pragma unroll
  for (int i = 0; i < 4; ++i) {
    int row_base = m0 + wr * 64 + i * 16 + lhi * 4;
#pragma unroll
    for (int j = 0; j < 4; ++j) {
      int col = n0 + wc * 64 + j * 16 + l16;
      float bv = ADD_BIAS ? bias[col] : 0.0f;
#pragma unroll
      for (int r = 0; r < 4; ++r) {
        float val = acc[i][j][r] + bv;
        if constexpr (__is_same(TC, float))
          C[(size_t)(row_base + r) * N + col] = val;
        else
          C[(size_t)(row_base + r) * N + col] = (bf16)val;
      }
    }
  }
}

// ---------------------------------------------------------------------------
// MFMA flash attention v8: 32 q-rows per wave (two 16-row sub-tiles A/B).
//  - Amortizes K/V staging, prefetch, and Vt reads over 2x MFMA work:
//    K-frags feed 2 MFMAs each; Vt read ONCE for PV_A+PV_B; block count
//    halves. (r6: MfmaUtil 16%, VALU 44%, 40% stalled on per-tile overhead.)
//  - Pq WAR (pfA read -> PqB write, same addrs) is safe: same-wave DS ops
//    execute in order.
//  - K+V double-buffer LDS, 1-tile prefetch, XCD swizzle, shuffle-free
//    softmax, defer-max, exp2-direct, setprio: all kept (r5 proven).
// ---------------------------------------------------------------------------
__global__ __launch_bounds__(256) void attn_fwd(bf16* __restrict__ qkv) {
  constexpr int S = 2048, D3 = 3072;
  constexpr float SCL = 0.18033688011112042f;  // 0.125 * log2(e)
  constexpr float THR = 11.5f;                 // 8 * log2(e)
  __shared__ __align__(16) bf16 Kt[2][64][72];  // [buf][key][dim]
  __shared__ __align__(16) bf16 Vt[2][64][72];  // [buf][dim][key]
  __shared__ __align__(16) bf16 Pq[4][16][72];  // per-wave transpose buffer

  const int tid = threadIdx.x;
  const int lane = tid & 63;
  const int wid = tid >> 6;
  const int l16 = lane & 15, lhi = lane >> 4;

  // XCD-aware bijective swizzle (nwg % 8 == 0 in all launch paths).
  const int nwg = gridDim.x * gridDim.y;  // 1024 (full) / 256 (fallback)
  const int bid = blockIdx.y * gridDim.x + blockIdx.x;
  const int swz = (bid & 7) * (nwg >> 3) + (bid >> 3);
  const int bh = swz >> 4;                // 16 q-tiles (128 rows) per bh
  const int b = bh >> 4, h = bh & 15;
  const int q0 = (swz & 15) * 128 + wid * 32;  // wave owns rows q0..q0+31

  bf16* base = qkv + (size_t)b * S * D3;
  bf16* qbase = base + h * 64;
  const bf16* kbase = base + 1024 + h * 64;
  const bf16* vbase = base + 2048 + h * 64;

  // Q fragments for both sub-tiles (cached before in-place overwrite)
  bf16x8 qfA[2], qfB[2];
#pragma unroll
  for (int ks = 0; ks < 2; ++ks) {
    qfA[ks] = *(const bf16x8*)(qbase + (size_t)(q0 + l16) * D3 + ks * 32 + lhi * 8);
    qfB[ks] = *(const bf16x8*)(qbase + (size_t)(q0 + 16 + l16) * D3 + ks * 32 + lhi * 8);
  }

  float mA = -1e30f, mB = -1e30f;   // running max, log2 domain
  float lA = 0.0f, lB = 0.0f;       // per-lane partial sums
  f32x4 oA[4] = {}, oB[4] = {};

  const int kp = tid & 31, oc = tid >> 5;  // stages keys 2kp,2kp+1, dims oc*8..+7

  // prologue: stage K(0), V(0) into buffer 0
  {
    bf16x8 k0 = *(const bf16x8*)(kbase + (size_t)(2 * kp) * D3 + oc * 8);
    bf16x8 k1 = *(const bf16x8*)(kbase + (size_t)(2 * kp + 1) * D3 + oc * 8);
    bf16x8 v0 = *(const bf16x8*)(vbase + (size_t)(2 * kp) * D3 + oc * 8);
    bf16x8 v1 = *(const bf16x8*)(vbase + (size_t)(2 * kp + 1) * D3 + oc * 8);
    *(bf16x8*)(&Kt[0][2 * kp][oc * 8]) = k0;
    *(bf16x8*)(&Kt[0][2 * kp + 1][oc * 8]) = k1;
#pragma unroll
    for (int j = 0; j < 8; ++j) {
      bf16x2 pr;
      pr[0] = v0[j];
      pr[1] = v1[j];
      *(bf16x2*)(&Vt[0][oc * 8 + j][2 * kp]) = pr;
    }
  }
  __syncthreads();

  for (int t = 0; t < S; t += 64) {
    const int cur = (t >> 6) & 1;
    const bool havenext = (t + 64 < S);

    // issue next tile's K+V global loads FIRST
    bf16x8 kn0, kn1, vn0, vn1;
    if (havenext) {
      const bf16* kb = kbase + (size_t)(t + 64) * D3;
      const bf16* vb = vbase + (size_t)(t + 64) * D3;
      kn0 = *(const bf16x8*)(kb + (size_t)(2 * kp) * D3 + oc * 8);
      kn1 = *(const bf16x8*)(kb + (size_t)(2 * kp + 1) * D3 + oc * 8);
      vn0 = *(const bf16x8*)(vb + (size_t)(2 * kp) * D3 + oc * 8);
      vn1 = *(const bf16x8*)(vb + (size_t)(2 * kp + 1) * D3 + oc * 8);
    }

    // K·Q^T for both sub-tiles: each K-frag feeds 2 MFMAs
    f32x4 scA[4] = {}, scB[4] = {};
    __builtin_amdgcn_s_setprio(1);
#pragma unroll
    for (int ct = 0; ct < 4; ++ct) {
#pragma unroll
      for (int ks = 0; ks < 2; ++ks) {
        bf16x8 kf = *(const bf16x8*)(&Kt[cur][ct * 16 + l16][ks * 32 + lhi * 8]);
        scA[ct] = __builtin_amdgcn_mfma_f32_16x16x32_bf16(kf, qfA[ks], scA[ct], 0, 0, 0);
        scB[ct] = __builtin_amdgcn_mfma_f32_16x16x32_bf16(kf, qfB[ks], scB[ct], 0, 0, 0);
      }
    }
    __builtin_amdgcn_s_setprio(0);

    // ---- softmax A ----
    {
      float cm[4];
#pragma unroll
      for (int ct = 0; ct < 4; ++ct)
        cm[ct] = fmaxf(fmaxf(scA[ct][0], scA[ct][1]), fmaxf(scA[ct][2], scA[ct][3]));
      float mxs = fmaxf(fmaxf(cm[0], cm[1]), fmaxf(cm[2], cm[3])) * SCL;
      if (!__all(mxs - mA <= THR)) {
        float mw = mxs;
        mw = fmaxf(mw, __shfl_xor(mw, 16));
        mw = fmaxf(mw, __shfl_xor(mw, 32));
        float nm = fmaxf(mA, mw);
        float alpha = __builtin_amdgcn_exp2f(mA - nm);
        mA = nm;
        lA *= alpha;
#pragma unroll
        for (int dt = 0; dt < 4; ++dt)
#pragma unroll
          for (int r = 0; r < 4; ++r) oA[dt][r] *= alpha;
      }
      float rs4[4];
#pragma unroll
      for (int ct = 0; ct < 4; ++ct) {
#pragma unroll
        for (int r = 0; r < 4; ++r) {
          float p = __builtin_amdgcn_exp2f(__builtin_fmaf(scA[ct][r], SCL, -mA));
          scA[ct][r] = p;
        }
        rs4[ct] = (scA[ct][0] + scA[ct][1]) + (scA[ct][2] + scA[ct][3]);
      }
      lA += (rs4[0] + rs4[1]) + (rs4[2] + rs4[3]);
    }
    // P-stage A + fragment reads
#pragma unroll
    for (int ct = 0; ct < 4; ++ct) {
      bf16x4 pk;
#pragma unroll
      for (int r = 0; r < 4; ++r) pk[r] = (bf16)scA[ct][r];
      *(bf16x4*)(&Pq[wid][l16][ct * 16 + lhi * 4]) = pk;
    }
    bf16x8 pfA0 = *(const bf16x8*)(&Pq[wid][l16][lhi * 8]);
    bf16x8 pfA1 = *(const bf16x8*)(&Pq[wid][l16][32 + lhi * 8]);

    // ---- softmax B ----
    {
      float cm[4];
#pragma unroll
      for (int ct = 0; ct < 4; ++ct)
        cm[ct] = fmaxf(fmaxf(scB[ct][0], scB[ct][1]), fmaxf(scB[ct][2], scB[ct][3]));
      float mxs = fmaxf(fmaxf(cm[0], cm[1]), fmaxf(cm[2], cm[3])) * SCL;
      if (!__all(mxs - mB <= THR)) {
        float mw = mxs;
        mw = fmaxf(mw, __shfl_xor(mw, 16));
        mw = fmaxf(mw, __shfl_xor(mw, 32));
        float nm = fmaxf(mB, mw);
        float alpha = __builtin_amdgcn_exp2f(mB - nm);
        mB = nm;
        lB *= alpha;
#pragma unroll
        for (int dt = 0; dt < 4; ++dt)
#pragma unroll
          for (int r = 0; r < 4; ++r) oB[dt][r] *= alpha;
      }
      float rs4[4];
#pragma unroll
      for (int ct = 0; ct < 4; ++ct) {
#pragma unroll
        for (int r = 0; r < 4; ++r) {
          float p = __builtin_amdgcn_exp2f(__builtin_fmaf(scB[ct][r], SCL, -mB));
          scB[ct][r] = p;
        }
        rs4[ct] = (scB[ct][0] + scB[ct][1]) + (scB[ct][2] + scB[ct][3]);
      }
      lB += (rs4[0] + rs4[1]) + (rs4[2] + rs4[3]);
    }
    // P-stage B (WAR vs pfA reads: same-wave DS in-order) + fragment reads
#pragma unroll
    for (int ct = 0; ct < 4; ++ct) {
      bf16x4 pk;
#pragma unroll
      for (int r = 0; r < 4; ++r) pk[r] = (bf16)scB[ct][r];
      *(bf16x4*)(&Pq[wid][l16][ct * 16 + lhi * 4]) = pk;
    }
    bf16x8 pfB0 = *(const bf16x8*)(&Pq[wid][l16][lhi * 8]);
    bf16x8 pfB1 = *(const bf16x8*)(&Pq[wid][l16][32 + lhi * 8]);

    // stage K(t+1), V(t+1) into the other buffer
    if (havenext) {
      *(bf16x8*)(&Kt[cur ^ 1][2 * kp][oc * 8]) = kn0;
      *(bf16x8*)(&Kt[cur ^ 1][2 * kp + 1][oc * 8]) = kn1;
#pragma unroll
      for (int j = 0; j < 8; ++j) {
        bf16x2 pr;
        pr[0] = vn0[j];
        pr[1] = vn1[j];
        *(bf16x2*)(&Vt[cur ^ 1][oc * 8 + j][2 * kp]) = pr;
      }
    }

    // PV for both sub-tiles: Vt read ONCE, feeds 4 MFMAs per dt
    __builtin_amdgcn_s_setprio(1);
#pragma unroll
    for (int dt = 0; dt < 4; ++dt) {
      bf16x8 vf0 = *(const bf16x8*)(&Vt[cur][dt * 16 + l16][lhi * 8]);
      bf16x8 vf1 = *(const bf16x8*)(&Vt[cur][dt * 16 + l16][32 + lhi * 8]);
      oA[dt] = __builtin_amdgcn_mfma_f32_16x16x32_bf16(vf0, pfA0, oA[dt], 0, 0, 0);
      oA[dt] = __builtin_amdgcn_mfma_f32_16x16x32_bf16(vf1, pfA1, oA[dt], 0, 0, 0);
      oB[dt] = __builtin_amdgcn_mfma_f32_16x16x32_bf16(vf0, pfB0, oB[dt], 0, 0, 0);
      oB[dt] = __builtin_amdgcn_mfma_f32_16x16x32_bf16(vf1, pfB1, oB[dt], 0, 0, 0);
    }
    __builtin_amdgcn_s_setprio(0);

    // single barrier: retires this tile's LDS reads, publishes buffer cur^1
    __syncthreads();
  }

  // epilogue A: reduce l, normalize, transpose via Pq, 16B stores
  {
    float l_i = lA;
    l_i += __shfl_xor(l_i, 16);
    l_i += __shfl_xor(l_i, 32);
    float rl = 1.0f / l_i;
#pragma unroll
    for (int dt = 0; dt < 4; ++dt) {
      bf16x4 ok;
#pragma unroll
      for (int r = 0; r < 4; ++r) ok[r] = (bf16)(oA[dt][r] * rl);
      *(bf16x4*)(&Pq[wid][l16][dt * 16 + lhi * 4]) = ok;
    }
    bf16x8 r0 = *(const bf16x8*)(&Pq[wid][l16][lhi * 16]);
    bf16x8 r1 = *(const bf16x8*)(&Pq[wid][l16][lhi * 16 + 8]);
    bf16* orow = qbase + (size_t)(q0 + l16) * D3 + lhi * 16;
    *(bf16x8*)(orow) = r0;
    *(bf16x8*)(orow + 8) = r1;
  }
  // epilogue B (Pq WAR safe: same-wave DS in-order)
  {
    float l_i = lB;
    l_i += __shfl_xor(l_i, 16);
    l_i += __shfl_xor(l_i, 32);
    float rl = 1.0f / l_i;
#pragma unroll
    for (int dt = 0; dt < 4; ++dt) {
      bf16x4 ok;
#pragma unroll
      for (int r = 0; r < 4; ++r) ok[r] = (bf16)(oB[dt][r] * rl);
      *(bf16x4*)(&Pq[wid][l16][dt * 16 + lhi * 4]) = ok;
    }
    bf16x8 r0 = *(const bf16x8*)(&Pq[wid][l16][lhi * 16]);
    bf16x8 r1 = *(const bf16x8*)(&Pq[wid][l16][lhi * 16 + 8]);
    bf16* orow = qbase + (size_t)(q0 + 16 + l16) * D3 + lhi * 16;
    *(bf16x8*)(orow) = r0;
    *(bf16x8*)(orow + 8) = r1;
  }
}

// ---------------------------------------------------------------------------
extern "C" void kernel_launch(void* const* d_in, const int* in_sizes, int n_in,
                              void* d_out, int out_size, void* d_ws,
                              size_t ws_size, hipStream_t stream) {
  constexpr int B = 4, S = 2048, D = 1024;

  const float* x = nullptr;
  const float* w_in = nullptr;
  const float* w_out = nullptr;
  const float* b_out = nullptr;
  for (int i = 0; i < n_in; ++i) {
    switch (in_sizes[i]) {
      case 8388608: x = (const float*)d_in[i]; break;
      case 3145728: w_in = (const float*)d_in[i]; break;
      case 1048576: w_out = (const float*)d_in[i]; break;
      case 1024: b_out = (const float*)d_in[i]; break;
    }
  }
  float* out = (float*)d_out;  // [4,2048,1024] fp32

  bf16* qkv = (bf16*)d_ws;
  const size_t need_full = (size_t)B * S * 3 * D * 2;      // 48 MiB (qkv)
  const size_t need_cvt = need_full +
                          ((size_t)B * S * D +              // x  bf16
                           (size_t)3 * D * D +              // w_in bf16
                           (size_t)D * D) * 2;              // w_out bf16

  if (ws_size >= need_cvt) {
    bf16* xb = qkv + (size_t)B * S * 3 * D;
    bf16* w_inb = xb + (size_t)B * S * D;
    bf16* w_outb = w_inb + (size_t)3 * D * D;
    const int nx8 = B * S * D / 8;
    const int nwi8 = 3 * D * D / 8;
    const int nwo8 = D * D / 8;
    cvt_bf16<<<dim3((nx8 + 255) / 256), 256, 0, stream>>>(x, xb, nx8);
    cvt_bf16<<<dim3((nwi8 + 255) / 256), 256, 0, stream>>>(w_in, w_inb, nwi8);
    cvt_bf16<<<dim3((nwo8 + 255) / 256), 256, 0, stream>>>(w_out, w_outb, nwo8);

    gemm_glds<bf16, false><<<dim3(3 * D / 128, B * S / 128), 256, 0, stream>>>(
        xb, w_inb, nullptr, qkv, B * S, 3 * D, D, D);
    attn_fwd<<<dim3(S / 128, B * 16), 256, 0, stream>>>(qkv);
    gemm_glds<float, true><<<dim3(D / 128, B * S / 128), 256, 0, stream>>>(
        qkv, w_outb, b_out, out, B * S, D, D, 3 * D);
  } else if (ws_size >= need_full) {
    gemm_bt<float, bf16, false><<<dim3(3 * D / 128, B * S / 128), 256, 0,
                                  stream>>>(x, w_in, nullptr, qkv, B * S,
                                            3 * D, D, D, 0);
    attn_fwd<<<dim3(S / 128, B * 16), 256, 0, stream>>>(qkv);
    gemm_bt<bf16, float, true><<<dim3(D / 128, B * S / 128), 256, 0, stream>>>(
        qkv, w_out, b_out, out, B * S, D, D, 3 * D, 0);
  } else {
    for (int b0 = 0; b0 < B; ++b0) {
      gemm_bt<float, bf16, false><<<dim3(3 * D / 128, S / 128), 256, 0,
                                    stream>>>(x, w_in, nullptr, qkv, S, 3 * D,
                                              D, D, b0 * S);
      attn_fwd<<<dim3(S / 128, 16), 256, 0, stream>>>(qkv);
      gemm_bt<bf16, float, true><<<dim3(D / 128, S / 128), 256, 0, stream>>>(
          qkv, w_out, b_out, out + (size_t)b0 * S * D, S, D, D, 3 * D, 0);
    }
  }
}